// Round 12
// baseline (153.608 us; speedup 1.0000x reference)
//
#include <hip/hip_runtime.h>

#define TT 2048
#define DD 1024
#define HH 16
#define DKK 64
#define BB 2

typedef __attribute__((ext_vector_type(8))) short bf16x8;
typedef __attribute__((ext_vector_type(4))) short bf16x4;
typedef __attribute__((ext_vector_type(4))) float f32x4;
typedef __attribute__((ext_vector_type(4))) unsigned short us4;

__device__ __forceinline__ unsigned short f2bf(float f) {
  union { float f; unsigned int i; } v; v.f = f;
  unsigned int x = v.i;
  return (unsigned short)((x + 0x7fffu + ((x >> 16) & 1u)) >> 16);
}
__device__ __forceinline__ unsigned int cvtpk_bf16(float lo, float hi) {
  unsigned int r;
  asm("v_cvt_pk_bf16_f32 %0, %1, %2" : "=v"(r) : "v"(lo), "v"(hi));
  return r;
}
__device__ __forceinline__ void gload16(const void* g, void* l) {
  __builtin_amdgcn_global_load_lds((const __attribute__((address_space(1))) void*)g,
                                   (__attribute__((address_space(3))) void*)l,
                                   16, 0, 0);
}

#if defined(__has_builtin)
#if __has_builtin(__builtin_amdgcn_exp2f)
#define HAVE_EXP2 1
#endif
#if __has_builtin(__builtin_amdgcn_mfma_f32_16x16x16bf16_1k)
#define HAVE_MFMA16 1
#endif
#endif

__device__ __forceinline__ float fexp2(float x) {
#ifdef HAVE_EXP2
  return __builtin_amdgcn_exp2f(x);
#else
  return __builtin_exp2f(x);
#endif
}

__device__ __forceinline__ f32x4 mfma16(bf16x4 a, bf16x4 b, f32x4 c) {
#ifdef HAVE_MFMA16
  return __builtin_amdgcn_mfma_f32_16x16x16bf16_1k(a, b, c, 0, 0, 0);
#else
  asm volatile("v_mfma_f32_16x16x16_bf16 %0, %1, %2, %0\n\ts_nop 7\n\ts_nop 7"
               : "+v"(c) : "v"(a), "v"(b));
  return c;
#endif
}

// fp32 -> bf16 for k,q,v,W in one dispatch
__global__ __launch_bounds__(256)
void f2b_all(const float* __restrict__ k, const float* __restrict__ q,
             const float* __restrict__ v, const float* __restrict__ W,
             unsigned short* __restrict__ kb, unsigned short* __restrict__ qb,
             unsigned short* __restrict__ vb, unsigned short* __restrict__ Wb)
{
  const int n1 = (BB * TT * DD) / 4;   // 1048576 float4s per tensor
  const int nW = (DD * DD) / 4;        // 262144
  const int total = 3 * n1 + nW;
  int i = blockIdx.x * 256 + threadIdx.x;
  const int stride = gridDim.x * 256;
  for (; i < total; i += stride) {
    const float* src; unsigned short* dst; int j = i;
    if (j < n1)            { src = k; dst = kb; }
    else if (j < 2 * n1)   { src = q; dst = qb; j -= n1; }
    else if (j < 3 * n1)   { src = v; dst = vb; j -= 2 * n1; }
    else                   { src = W; dst = Wb; j -= 3 * n1; }
    const float4 f = ((const float4*)src)[j];
    us4 o;
    o[0] = f2bf(f.x); o[1] = f2bf(f.y); o[2] = f2bf(f.z); o[3] = f2bf(f.w);
    ((us4*)dst)[j] = o;
  }
}

// ---- shared GEMM tile machinery (128x128 tile, BK=32, 4 waves) ----
// LDS rows are 64B; XOR-swizzle (row&3)<<4 via pre-swizzled global source.
// Bijective XCD swizzle keeps A-strip-sharing blocks on one XCD (T1).

// Fused K/Q/V projection: 768 blocks; virt id: n fast (8), m-strip (96) slow.
__global__ __launch_bounds__(256)
void gemm_proj(const unsigned short* __restrict__ kb, const unsigned short* __restrict__ qb,
               const unsigned short* __restrict__ vb, const unsigned short* __restrict__ W,
               const float* __restrict__ bias,
               unsigned short* __restrict__ Kp, unsigned short* __restrict__ Qp,
               unsigned short* __restrict__ Vt)
{
  __shared__ unsigned short lA[2][128 * 32];
  __shared__ unsigned short lB[2][128 * 32];
  const int tid = threadIdx.x;
  const int w = tid >> 6, l = tid & 63;
  const int hw = blockIdx.y * gridDim.x + blockIdx.x;     // 0..767
  const int virt = (hw & 7) * 96 + (hw >> 3);
  const int n0 = (virt & 7) * 128;
  const int my = virt >> 3;                                // 0..95
  const int grp = my >> 5;                                 // 0:K 1:Q 2:V
  const int m0 = (my & 31) * 128;
  const unsigned short* A = grp == 0 ? kb : (grp == 1 ? qb : vb);
  const int wr = w >> 1, wc = w & 1;
  const int lg = l >> 4, lc = l & 15;

  f32x4 acc[4][4];
#pragma unroll
  for (int i = 0; i < 4; ++i)
#pragma unroll
    for (int j = 0; j < 4; ++j) acc[i][j] = (f32x4){0.f, 0.f, 0.f, 0.f};

  const int scolb = (((l & 3) ^ ((l >> 2) & 3)) * 16);  // pre-swizzled source slot

  auto stage = [&](int buf, int k0) {
#pragma unroll
    for (int cc = 0; cc < 2; ++cc) {
      const int slot = w * 2 + cc;
      const int row = slot * 16 + (l >> 2);
      gload16(A + (size_t)(m0 + row) * DD + k0 + (scolb >> 1), &lA[buf][slot * 512]);
      gload16(W + (size_t)(n0 + row) * DD + k0 + (scolb >> 1), &lB[buf][slot * 512]);
    }
  };

  stage(0, 0);
  __syncthreads();
  int cur = 0;
#pragma unroll 1
  for (int kt = 0; kt < 32; ++kt) {
    if (kt < 31) stage(cur ^ 1, (kt + 1) * 32);
    const char* la = (const char*)lA[cur];
    const char* lb = (const char*)lB[cur];
    bf16x8 af[4], bfr[4];
#pragma unroll
    for (int mf = 0; mf < 4; ++mf)
      af[mf] = *(const bf16x8*)(la + (wr * 64 + mf * 16 + lc) * 64 + ((lg * 16) ^ ((lc & 3) << 4)));
#pragma unroll
    for (int nf = 0; nf < 4; ++nf)
      bfr[nf] = *(const bf16x8*)(lb + (wc * 64 + nf * 16 + lc) * 64 + ((lg * 16) ^ ((lc & 3) << 4)));
#pragma unroll
    for (int mf = 0; mf < 4; ++mf)
#pragma unroll
      for (int nf = 0; nf < 4; ++nf)
        acc[mf][nf] = __builtin_amdgcn_mfma_f32_16x16x32_bf16(af[mf], bfr[nf], acc[mf][nf], 0, 0, 0);
    __syncthreads();
    cur ^= 1;
  }

  // Q gets 1/sqrt(DK) * log2(e) folded in (attn softmax runs in exp2 domain)
  const float scale = (grp == 1) ? 0.125f * 1.4426950408889634f : 1.0f;
#pragma unroll
  for (int nf = 0; nf < 4; ++nf) {
    const int colg = n0 + wc * 64 + nf * 16 + lc;
    const float bv = bias[colg];
#pragma unroll
    for (int mf = 0; mf < 4; ++mf) {
      const int rowg = m0 + wr * 64 + mf * 16 + lg * 4;
      if (grp < 2) {
        unsigned short* C = grp == 0 ? Kp : Qp;
#pragma unroll
        for (int r = 0; r < 4; ++r)
          C[(size_t)(rowg + r) * DD + colg] = f2bf(scale * (acc[mf][nf][r] + bv));
      } else {
        const int bb = rowg >> 11, t = rowg & (TT - 1);
        const int hh = colg >> 6, dk = colg & 63;
        us4 pk;
#pragma unroll
        for (int r = 0; r < 4; ++r) pk[r] = f2bf(acc[mf][nf][r] + bv);
        *(us4*)&Vt[((size_t)((bb * HH + hh) * DKK + dk)) * TT + t] = pk;
      }
    }
  }
}

// Final projection: C(fp32) = A @ W^T + bias; 256 blocks, XCD-swizzled.
__global__ __launch_bounds__(256)
void gemm_out(const unsigned short* __restrict__ A, const unsigned short* __restrict__ W,
              const float* __restrict__ bias, float* __restrict__ Cf)
{
  __shared__ unsigned short lA[2][128 * 32];
  __shared__ unsigned short lB[2][128 * 32];
  const int tid = threadIdx.x;
  const int w = tid >> 6, l = tid & 63;
  const int hw = blockIdx.y * gridDim.x + blockIdx.x;     // 0..255
  const int virt = (hw & 7) * 32 + (hw >> 3);
  const int n0 = (virt & 7) * 128, m0 = (virt >> 3) * 128;
  const int wr = w >> 1, wc = w & 1;
  const int lg = l >> 4, lc = l & 15;

  f32x4 acc[4][4];
#pragma unroll
  for (int i = 0; i < 4; ++i)
#pragma unroll
    for (int j = 0; j < 4; ++j) acc[i][j] = (f32x4){0.f, 0.f, 0.f, 0.f};

  const int scolb = (((l & 3) ^ ((l >> 2) & 3)) * 16);

  auto stage = [&](int buf, int k0) {
#pragma unroll
    for (int cc = 0; cc < 2; ++cc) {
      const int slot = w * 2 + cc;
      const int row = slot * 16 + (l >> 2);
      gload16(A + (size_t)(m0 + row) * DD + k0 + (scolb >> 1), &lA[buf][slot * 512]);
      gload16(W + (size_t)(n0 + row) * DD + k0 + (scolb >> 1), &lB[buf][slot * 512]);
    }
  };

  stage(0, 0);
  __syncthreads();
  int cur = 0;
#pragma unroll 1
  for (int kt = 0; kt < 32; ++kt) {
    if (kt < 31) stage(cur ^ 1, (kt + 1) * 32);
    const char* la = (const char*)lA[cur];
    const char* lb = (const char*)lB[cur];
    bf16x8 af[4], bfr[4];
#pragma unroll
    for (int mf = 0; mf < 4; ++mf)
      af[mf] = *(const bf16x8*)(la + (wr * 64 + mf * 16 + lc) * 64 + ((lg * 16) ^ ((lc & 3) << 4)));
#pragma unroll
    for (int nf = 0; nf < 4; ++nf)
      bfr[nf] = *(const bf16x8*)(lb + (wc * 64 + nf * 16 + lc) * 64 + ((lg * 16) ^ ((lc & 3) << 4)));
#pragma unroll
    for (int mf = 0; mf < 4; ++mf)
#pragma unroll
      for (int nf = 0; nf < 4; ++nf)
        acc[mf][nf] = __builtin_amdgcn_mfma_f32_16x16x32_bf16(af[mf], bfr[nf], acc[mf][nf], 0, 0, 0);
    __syncthreads();
    cur ^= 1;
  }

#pragma unroll
  for (int nf = 0; nf < 4; ++nf) {
    const int colg = n0 + wc * 64 + nf * 16 + lc;
    const float bv = bias[colg];
#pragma unroll
    for (int mf = 0; mf < 4; ++mf) {
      const int rowg = m0 + wr * 64 + mf * 16 + lg * 4;
#pragma unroll
      for (int r = 0; r < 4; ++r)
        Cf[(size_t)(rowg + r) * DD + colg] = acc[mf][nf][r] + bv;
    }
  }
}

// Flash attention, DUAL-STREAM: each block processes q-blocks qi*64 (part 0,
// n0 = qi+1 tiles) and (31-qi)*64 (part 1, n1 = 32-qi tiles) in ONE fused
// tile loop over the shared K/V sequence. Each LDS fragment (kf, vb) is read
// once and feeds both parts' MFMAs (attn is LDS-BW-bound; reads are the cost).
// Part 0 is gated by the uniform branch t < n0. Per-part math is identical
// to the round-7/9 proven body. Grid (32, 16): x = b*16+h, y = qi.
__global__ __launch_bounds__(256)
void attn(const unsigned short* __restrict__ Qp,
          const unsigned short* __restrict__ Kp,
          const unsigned short* __restrict__ Vt,
          const int* __restrict__ maskp,
          const int* __restrict__ causalp,
          unsigned short* __restrict__ Oc)
{
  __shared__ unsigned short Kl[2][64 * 64];
  __shared__ unsigned short Vl[2][64 * 64];
  const int tid = threadIdx.x;
  const int w = tid >> 6, l = tid & 63;
  const int bh = blockIdx.x;
  const int qi = blockIdx.y;                // 0..15
  const int b = bh >> 4, h = bh & 15;
  const int lg = l >> 4, lc = l & 15;
  const int causal = causalp[0];

  const int q0a = qi * 64;                  // part 0
  const int q0b = (31 - qi) * 64;           // part 1
  const int n0 = causal ? (qi + 1) : (TT >> 6);
  const int n1 = causal ? (32 - qi) : (TT >> 6);   // n1 >= n0 always
  const int qra = q0a + w * 16 + lc;
  const int qrb = q0b + w * 16 + lc;

  // Q as B-operand: col=lc -> q-row, d = kk*32 + lg*8 + j
  bf16x8 qfa[2], qfb[2];
  {
    const unsigned short* qp = Qp + (size_t)(b * TT + qra) * DD + h * DKK + lg * 8;
    qfa[0] = *(const bf16x8*)qp;
    qfa[1] = *(const bf16x8*)(qp + 32);
    const unsigned short* qp2 = Qp + (size_t)(b * TT + qrb) * DD + h * DKK + lg * 8;
    qfb[0] = *(const bf16x8*)qp2;
    qfb[1] = *(const bf16x8*)(qp2 + 32);
  }
  f32x4 oa[4], ob[4];
#pragma unroll
  for (int nfo = 0; nfo < 4; ++nfo) {
    oa[nfo] = (f32x4){0.f, 0.f, 0.f, 0.f};
    ob[nfo] = (f32x4){0.f, 0.f, 0.f, 0.f};
  }
  float ma = -1e30f, la = 0.f, mb = -1e30f, lb_ = 0.f;

  const int swz = ((l & 7) ^ (l >> 3)) * 16;  // pre-swizzled source slot (bytes)
  int kcoff[2], vcoff[4];
#pragma unroll
  for (int kk = 0; kk < 2; ++kk) kcoff[kk] = (kk * 64 + lg * 16) ^ ((lc & 7) << 4);
#pragma unroll
  for (int nfk = 0; nfk < 4; ++nfk) vcoff[nfk] = (nfk * 32 + lg * 8) ^ ((lc & 7) << 4);
  const int rowb = lc * 128;                  // byte offset of this lane's LDS row
  const int* mrow = maskp + b * TT;

  auto stage = [&](int buf, int c0) {
#pragma unroll
    for (int cc = 0; cc < 2; ++cc) {
      const int slot = w * 2 + cc;
      const int rr = slot * 8 + (l >> 3);
      gload16(Kp + (size_t)(b * TT + c0 + rr) * DD + h * DKK + (swz >> 1), &Kl[buf][slot * 512]);
      gload16(Vt + (size_t)((b * HH + h) * DKK + rr) * TT + c0 + (swz >> 1), &Vl[buf][slot * 512]);
    }
  };

  // per-part softmax: updates (m, lsum), produces pa[] from s[]
  auto softmax = [&](f32x4 (&s)[4], float& m, float& lsum, bf16x4 (&pa)[4],
                     f32x4 (&o)[4]) {
    float pm = fmaxf(fmaxf(fmaxf(s[0][0], s[0][1]), fmaxf(s[0][2], s[0][3])),
                     fmaxf(fmaxf(s[1][0], s[1][1]), fmaxf(s[1][2], s[1][3])));
    pm = fmaxf(pm, fmaxf(fmaxf(fmaxf(s[2][0], s[2][1]), fmaxf(s[2][2], s[2][3])),
                         fmaxf(fmaxf(s[3][0], s[3][1]), fmaxf(s[3][2], s[3][3]))));
    pm = fmaxf(pm, __shfl_xor(pm, 16, 64));
    pm = fmaxf(pm, __shfl_xor(pm, 32, 64));
    const float mn = fmaxf(fmaxf(m, pm), -1e28f);
    const float al = fexp2(m - mn);
    m = mn;
    float alr[4];
#pragma unroll
    for (int r = 0; r < 4; ++r) alr[r] = __shfl(al, lg * 4 + r, 64);
#pragma unroll
    for (int nfo = 0; nfo < 4; ++nfo)
#pragma unroll
      for (int r = 0; r < 4; ++r) o[nfo][r] *= alr[r];
    float ps = 0.f;
#pragma unroll
    for (int nf = 0; nf < 4; ++nf) {
      const float p0 = fexp2(s[nf][0] - m);
      const float p1 = fexp2(s[nf][1] - m);
      const float p2 = fexp2(s[nf][2] - m);
      const float p3 = fexp2(s[nf][3] - m);
      ps += (p0 + p1) + (p2 + p3);
      union { unsigned int u[2]; bf16x4 v; } pk;
      pk.u[0] = cvtpk_bf16(p0, p1);
      pk.u[1] = cvtpk_bf16(p2, p3);
      pa[nf] = pk.v;
    }
    ps += __shfl_xor(ps, 16, 64);
    ps += __shfl_xor(ps, 32, 64);
    lsum = lsum * al + ps;
  };

  stage(0, 0);
  __syncthreads();
  int cur = 0;
#pragma unroll 1
  for (int t = 0; t < n1; ++t) {
    if (t + 1 < n1) stage(cur ^ 1, (t + 1) * 64);
    const int c0 = t * 64;
    const char* kl = (const char*)Kl[cur];
    const char* vl = (const char*)Vl[cur];
    const bool act0 = (t < n0);   // uniform across block

    // S^T = mfma(K, Q): each kf fragment read once, feeds both parts
    f32x4 sa[4], sb[4];
#pragma unroll
    for (int nf = 0; nf < 4; ++nf) {
      sa[nf] = (f32x4){0.f, 0.f, 0.f, 0.f};
      sb[nf] = (f32x4){0.f, 0.f, 0.f, 0.f};
    }
#pragma unroll
    for (int nf = 0; nf < 4; ++nf)
#pragma unroll
      for (int kk = 0; kk < 2; ++kk) {
        bf16x8 kf = *(const bf16x8*)(kl + rowb + kcoff[kk] + nf * 2048);
        if (act0) sa[nf] = __builtin_amdgcn_mfma_f32_16x16x32_bf16(kf, qfa[kk], sa[nf], 0, 0, 0);
        sb[nf] = __builtin_amdgcn_mfma_f32_16x16x32_bf16(kf, qfb[kk], sb[nf], 0, 0, 0);
      }

    // padding mask (applies to both parts; fast path when tile fully alive)
    const unsigned long long bal = __ballot(mrow[c0 + l] != 0);
    if (bal != ~0ull) {
#pragma unroll
      for (int nf = 0; nf < 4; ++nf) {
        const int4 mv = *(const int4*)&mrow[c0 + nf * 16 + lg * 4];
        const int mvr[4] = {mv.x, mv.y, mv.z, mv.w};
#pragma unroll
        for (int r = 0; r < 4; ++r)
          if (mvr[r] == 0) { sa[nf][r] = -1e30f; sb[nf][r] = -1e30f; }
      }
    }
    // causal: diagonal tile per part only
    if (causal && act0 && (t == n0 - 1)) {
#pragma unroll
      for (int nf = 0; nf < 4; ++nf)
#pragma unroll
        for (int r = 0; r < 4; ++r) {
          const int kg = c0 + nf * 16 + lg * 4 + r;
          if (kg > qra) sa[nf][r] = -1e30f;
        }
    }
    if (causal && (t == n1 - 1)) {
#pragma unroll
      for (int nf = 0; nf < 4; ++nf)
#pragma unroll
        for (int r = 0; r < 4; ++r) {
          const int kg = c0 + nf * 16 + lg * 4 + r;
          if (kg > qrb) sb[nf][r] = -1e30f;
        }
    }

    bf16x4 paa[4], pab[4];
    if (act0) softmax(sa, ma, la, paa, oa);
    softmax(sb, mb, lb_, pab, ob);

    // O += P @ V: each vb fragment read once, feeds both parts
#pragma unroll
    for (int nfo = 0; nfo < 4; ++nfo)
#pragma unroll
      for (int nfk = 0; nfk < 4; ++nfk) {
        bf16x4 vb = *(const bf16x4*)(vl + rowb + vcoff[nfk] + nfo * 2048);
        if (act0) oa[nfo] = mfma16(paa[nfk], vb, oa[nfo]);
        ob[nfo] = mfma16(pab[nfk], vb, ob[nfo]);
      }

    __syncthreads();  // LDS reads of cur done; stage of cur^1 drained
    cur ^= 1;
  }

  // epilogue per part: l-normalize; lsum for q-row lg*4+r lives in lane (lg*4+r)
  {
    float linv[4];
#pragma unroll
    for (int r = 0; r < 4; ++r) linv[r] = 1.0f / __shfl(la, lg * 4 + r, 64);
#pragma unroll
    for (int nfo = 0; nfo < 4; ++nfo) {
      const int dg = h * DKK + nfo * 16 + lc;
#pragma unroll
      for (int r = 0; r < 4; ++r) {
        const int qg = q0a + w * 16 + lg * 4 + r;
        Oc[(size_t)(b * TT + qg) * DD + dg] = f2bf(oa[nfo][r] * linv[r]);
      }
    }
  }
  {
    float linv[4];
#pragma unroll
    for (int r = 0; r < 4; ++r) linv[r] = 1.0f / __shfl(lb_, lg * 4 + r, 64);
#pragma unroll
    for (int nfo = 0; nfo < 4; ++nfo) {
      const int dg = h * DKK + nfo * 16 + lc;
#pragma unroll
      for (int r = 0; r < 4; ++r) {
        const int qg = q0b + w * 16 + lg * 4 + r;
        Oc[(size_t)(b * TT + qg) * DD + dg] = f2bf(ob[nfo][r] * linv[r]);
      }
    }
  }
}

extern "C" void kernel_launch(void* const* d_in, const int* in_sizes, int n_in,
                              void* d_out, int out_size, void* d_ws, size_t ws_size,
                              hipStream_t stream)
{
  (void)in_sizes; (void)n_in; (void)out_size; (void)ws_size;
  const float* kf = (const float*)d_in[0];
  const float* qf = (const float*)d_in[1];
  const float* vf = (const float*)d_in[2];
  const int* mask = (const int*)d_in[3];
  const int* causal = (const int*)d_in[4];
  const float* Wf = (const float*)d_in[5];
  const float* bf = (const float*)d_in[6];

  const size_t MB = 1024 * 1024;
  char* ws = (char*)d_ws;
  unsigned short* kb = (unsigned short*)(ws);                 // 8 MiB
  unsigned short* qb = (unsigned short*)(ws + 8 * MB);        // 8 MiB
  unsigned short* vb = (unsigned short*)(ws + 16 * MB);       // 8 MiB
  unsigned short* Wb = (unsigned short*)(ws + 24 * MB);       // 2 MiB
  unsigned short* Kp = (unsigned short*)(ws + 26 * MB);       // 8 MiB
  unsigned short* Qp = (unsigned short*)(ws + 34 * MB);       // 8 MiB
  unsigned short* Vt = (unsigned short*)(ws + 42 * MB);       // 8 MiB
  unsigned short* Oc = kb;  // kb dead after projections

  f2b_all<<<dim3(2048), dim3(256), 0, stream>>>(kf, qf, vf, Wf, kb, qb, vb, Wb);
  gemm_proj<<<dim3(8, 96), dim3(256), 0, stream>>>(kb, qb, vb, Wb, bf, Kp, Qp, Vt);
  attn<<<dim3(32, 16), dim3(256), 0, stream>>>(Qp, Kp, Vt, mask, causal, Oc);
  gemm_out<<<dim3(8, 32), dim3(256), 0, stream>>>(Oc, Wb, bf, (float*)d_out);
}

// Round 13
// 134.334 us; speedup vs baseline: 1.1435x; 1.1435x over previous
//
#include <hip/hip_runtime.h>

#define TT 2048
#define DD 1024
#define HH 16
#define DKK 64
#define BB 2

typedef __attribute__((ext_vector_type(8))) short bf16x8;
typedef __attribute__((ext_vector_type(4))) short bf16x4;
typedef __attribute__((ext_vector_type(4))) float f32x4;
typedef __attribute__((ext_vector_type(4))) unsigned short us4;

__device__ __forceinline__ unsigned short f2bf(float f) {
  union { float f; unsigned int i; } v; v.f = f;
  unsigned int x = v.i;
  return (unsigned short)((x + 0x7fffu + ((x >> 16) & 1u)) >> 16);
}
__device__ __forceinline__ unsigned int cvtpk_bf16(float lo, float hi) {
  unsigned int r;
  asm("v_cvt_pk_bf16_f32 %0, %1, %2" : "=v"(r) : "v"(lo), "v"(hi));
  return r;
}
__device__ __forceinline__ void gload16(const void* g, void* l) {
  __builtin_amdgcn_global_load_lds((const __attribute__((address_space(1))) void*)g,
                                   (__attribute__((address_space(3))) void*)l,
                                   16, 0, 0);
}

#if defined(__has_builtin)
#if __has_builtin(__builtin_amdgcn_exp2f)
#define HAVE_EXP2 1
#endif
#if __has_builtin(__builtin_amdgcn_mfma_f32_16x16x16bf16_1k)
#define HAVE_MFMA16 1
#endif
#endif

__device__ __forceinline__ float fexp2(float x) {
#ifdef HAVE_EXP2
  return __builtin_amdgcn_exp2f(x);
#else
  return __builtin_exp2f(x);
#endif
}

__device__ __forceinline__ f32x4 mfma16(bf16x4 a, bf16x4 b, f32x4 c) {
#ifdef HAVE_MFMA16
  return __builtin_amdgcn_mfma_f32_16x16x16bf16_1k(a, b, c, 0, 0, 0);
#else
  asm volatile("v_mfma_f32_16x16x16_bf16 %0, %1, %2, %0\n\ts_nop 7\n\ts_nop 7"
               : "+v"(c) : "v"(a), "v"(b));
  return c;
#endif
}

// fp32 -> bf16 for k,q,v,W in one dispatch
__global__ __launch_bounds__(256)
void f2b_all(const float* __restrict__ k, const float* __restrict__ q,
             const float* __restrict__ v, const float* __restrict__ W,
             unsigned short* __restrict__ kb, unsigned short* __restrict__ qb,
             unsigned short* __restrict__ vb, unsigned short* __restrict__ Wb)
{
  const int n1 = (BB * TT * DD) / 4;   // 1048576 float4s per tensor
  const int nW = (DD * DD) / 4;        // 262144
  const int total = 3 * n1 + nW;
  int i = blockIdx.x * 256 + threadIdx.x;
  const int stride = gridDim.x * 256;
  for (; i < total; i += stride) {
    const float* src; unsigned short* dst; int j = i;
    if (j < n1)            { src = k; dst = kb; }
    else if (j < 2 * n1)   { src = q; dst = qb; j -= n1; }
    else if (j < 3 * n1)   { src = v; dst = vb; j -= 2 * n1; }
    else                   { src = W; dst = Wb; j -= 3 * n1; }
    const float4 f = ((const float4*)src)[j];
    us4 o;
    o[0] = f2bf(f.x); o[1] = f2bf(f.y); o[2] = f2bf(f.z); o[3] = f2bf(f.w);
    ((us4*)dst)[j] = o;
  }
}

// ---- shared GEMM tile machinery (128x128 tile, BK=32, 4 waves) ----
// LDS rows are 64B; XOR-swizzle (row&3)<<4 via pre-swizzled global source.
// Bijective XCD swizzle keeps A-strip-sharing blocks on one XCD (T1).

// Fused K/Q/V projection: 768 blocks; virt id: n fast (8), m-strip (96) slow.
__global__ __launch_bounds__(256)
void gemm_proj(const unsigned short* __restrict__ kb, const unsigned short* __restrict__ qb,
               const unsigned short* __restrict__ vb, const unsigned short* __restrict__ W,
               const float* __restrict__ bias,
               unsigned short* __restrict__ Kp, unsigned short* __restrict__ Qp,
               unsigned short* __restrict__ Vt)
{
  __shared__ unsigned short lA[2][128 * 32];
  __shared__ unsigned short lB[2][128 * 32];
  const int tid = threadIdx.x;
  const int w = tid >> 6, l = tid & 63;
  const int hw = blockIdx.y * gridDim.x + blockIdx.x;     // 0..767
  const int virt = (hw & 7) * 96 + (hw >> 3);
  const int n0 = (virt & 7) * 128;
  const int my = virt >> 3;                                // 0..95
  const int grp = my >> 5;                                 // 0:K 1:Q 2:V
  const int m0 = (my & 31) * 128;
  const unsigned short* A = grp == 0 ? kb : (grp == 1 ? qb : vb);
  const int wr = w >> 1, wc = w & 1;
  const int lg = l >> 4, lc = l & 15;

  f32x4 acc[4][4];
#pragma unroll
  for (int i = 0; i < 4; ++i)
#pragma unroll
    for (int j = 0; j < 4; ++j) acc[i][j] = (f32x4){0.f, 0.f, 0.f, 0.f};

  const int scolb = (((l & 3) ^ ((l >> 2) & 3)) * 16);  // pre-swizzled source slot

  auto stage = [&](int buf, int k0) {
#pragma unroll
    for (int cc = 0; cc < 2; ++cc) {
      const int slot = w * 2 + cc;
      const int row = slot * 16 + (l >> 2);
      gload16(A + (size_t)(m0 + row) * DD + k0 + (scolb >> 1), &lA[buf][slot * 512]);
      gload16(W + (size_t)(n0 + row) * DD + k0 + (scolb >> 1), &lB[buf][slot * 512]);
    }
  };

  stage(0, 0);
  __syncthreads();
  int cur = 0;
#pragma unroll 1
  for (int kt = 0; kt < 32; ++kt) {
    if (kt < 31) stage(cur ^ 1, (kt + 1) * 32);
    const char* la = (const char*)lA[cur];
    const char* lb = (const char*)lB[cur];
    bf16x8 af[4], bfr[4];
#pragma unroll
    for (int mf = 0; mf < 4; ++mf)
      af[mf] = *(const bf16x8*)(la + (wr * 64 + mf * 16 + lc) * 64 + ((lg * 16) ^ ((lc & 3) << 4)));
#pragma unroll
    for (int nf = 0; nf < 4; ++nf)
      bfr[nf] = *(const bf16x8*)(lb + (wc * 64 + nf * 16 + lc) * 64 + ((lg * 16) ^ ((lc & 3) << 4)));
#pragma unroll
    for (int mf = 0; mf < 4; ++mf)
#pragma unroll
      for (int nf = 0; nf < 4; ++nf)
        acc[mf][nf] = __builtin_amdgcn_mfma_f32_16x16x32_bf16(af[mf], bfr[nf], acc[mf][nf], 0, 0, 0);
    __syncthreads();
    cur ^= 1;
  }

  // Q gets 1/sqrt(DK) * log2(e) folded in (attn softmax runs in exp2 domain)
  const float scale = (grp == 1) ? 0.125f * 1.4426950408889634f : 1.0f;
#pragma unroll
  for (int nf = 0; nf < 4; ++nf) {
    const int colg = n0 + wc * 64 + nf * 16 + lc;
    const float bv = bias[colg];
#pragma unroll
    for (int mf = 0; mf < 4; ++mf) {
      const int rowg = m0 + wr * 64 + mf * 16 + lg * 4;
      if (grp < 2) {
        unsigned short* C = grp == 0 ? Kp : Qp;
#pragma unroll
        for (int r = 0; r < 4; ++r)
          C[(size_t)(rowg + r) * DD + colg] = f2bf(scale * (acc[mf][nf][r] + bv));
      } else {
        const int bb = rowg >> 11, t = rowg & (TT - 1);
        const int hh = colg >> 6, dk = colg & 63;
        us4 pk;
#pragma unroll
        for (int r = 0; r < 4; ++r) pk[r] = f2bf(acc[mf][nf][r] + bv);
        *(us4*)&Vt[((size_t)((bb * HH + hh) * DKK + dk)) * TT + t] = pk;
      }
    }
  }
}

// Final projection: C(fp32) = A @ W^T + bias; 256 blocks, XCD-swizzled.
__global__ __launch_bounds__(256)
void gemm_out(const unsigned short* __restrict__ A, const unsigned short* __restrict__ W,
              const float* __restrict__ bias, float* __restrict__ Cf)
{
  __shared__ unsigned short lA[2][128 * 32];
  __shared__ unsigned short lB[2][128 * 32];
  const int tid = threadIdx.x;
  const int w = tid >> 6, l = tid & 63;
  const int hw = blockIdx.y * gridDim.x + blockIdx.x;     // 0..255
  const int virt = (hw & 7) * 32 + (hw >> 3);
  const int n0 = (virt & 7) * 128, m0 = (virt >> 3) * 128;
  const int wr = w >> 1, wc = w & 1;
  const int lg = l >> 4, lc = l & 15;

  f32x4 acc[4][4];
#pragma unroll
  for (int i = 0; i < 4; ++i)
#pragma unroll
    for (int j = 0; j < 4; ++j) acc[i][j] = (f32x4){0.f, 0.f, 0.f, 0.f};

  const int scolb = (((l & 3) ^ ((l >> 2) & 3)) * 16);

  auto stage = [&](int buf, int k0) {
#pragma unroll
    for (int cc = 0; cc < 2; ++cc) {
      const int slot = w * 2 + cc;
      const int row = slot * 16 + (l >> 2);
      gload16(A + (size_t)(m0 + row) * DD + k0 + (scolb >> 1), &lA[buf][slot * 512]);
      gload16(W + (size_t)(n0 + row) * DD + k0 + (scolb >> 1), &lB[buf][slot * 512]);
    }
  };

  stage(0, 0);
  __syncthreads();
  int cur = 0;
#pragma unroll 1
  for (int kt = 0; kt < 32; ++kt) {
    if (kt < 31) stage(cur ^ 1, (kt + 1) * 32);
    const char* la = (const char*)lA[cur];
    const char* lb = (const char*)lB[cur];
    bf16x8 af[4], bfr[4];
#pragma unroll
    for (int mf = 0; mf < 4; ++mf)
      af[mf] = *(const bf16x8*)(la + (wr * 64 + mf * 16 + lc) * 64 + ((lg * 16) ^ ((lc & 3) << 4)));
#pragma unroll
    for (int nf = 0; nf < 4; ++nf)
      bfr[nf] = *(const bf16x8*)(lb + (wc * 64 + nf * 16 + lc) * 64 + ((lg * 16) ^ ((lc & 3) << 4)));
#pragma unroll
    for (int mf = 0; mf < 4; ++mf)
#pragma unroll
      for (int nf = 0; nf < 4; ++nf)
        acc[mf][nf] = __builtin_amdgcn_mfma_f32_16x16x32_bf16(af[mf], bfr[nf], acc[mf][nf], 0, 0, 0);
    __syncthreads();
    cur ^= 1;
  }

#pragma unroll
  for (int nf = 0; nf < 4; ++nf) {
    const int colg = n0 + wc * 64 + nf * 16 + lc;
    const float bv = bias[colg];
#pragma unroll
    for (int mf = 0; mf < 4; ++mf) {
      const int rowg = m0 + wr * 64 + mf * 16 + lg * 4;
#pragma unroll
      for (int r = 0; r < 4; ++r)
        Cf[(size_t)(rowg + r) * DD + colg] = acc[mf][nf][r] + bv;
    }
  }
}

// Flash attention (round-9 structure): swapped-operand QK^T, in-register P,
// exp2-domain softmax, QBLK=64, grid (32,32), heavy-first.
// NEW vs r9 (both shuffle-chain cuts, isolated):
//  - T13 defer-rescale: skip {1 exp + 4 shuffles + 16 muls} when the tile max
//    grew by <= 8 exp2-units (P bounded by 2^8; f32 accum absorbs it).
//  - lsum kept as per-lane PARTIAL (al is identical across the 4 lanes of a
//    q-row, so partials scale consistently); lg-reduce moved to the epilogue.
__global__ __launch_bounds__(256)
void attn(const unsigned short* __restrict__ Qp,
          const unsigned short* __restrict__ Kp,
          const unsigned short* __restrict__ Vt,
          const int* __restrict__ maskp,
          const int* __restrict__ causalp,
          unsigned short* __restrict__ Oc)
{
  __shared__ unsigned short Kl[2][64 * 64];
  __shared__ unsigned short Vl[2][64 * 64];
  const int tid = threadIdx.x;
  const int w = tid >> 6, l = tid & 63;
  const int bh = blockIdx.x;
  const int q0 = (31 - blockIdx.y) * 64;
  const int b = bh >> 4, h = bh & 15;
  const int lg = l >> 4, lc = l & 15;
  const int causal = causalp[0];
  const int qr = q0 + w * 16 + lc;          // this lane's q-row

  // Q as B-operand: col=lc -> q-row, d = kk*32 + lg*8 + j
  bf16x8 qf[2];
  {
    const unsigned short* qp = Qp + (size_t)(b * TT + qr) * DD + h * DKK + lg * 8;
    qf[0] = *(const bf16x8*)qp;
    qf[1] = *(const bf16x8*)(qp + 32);
  }
  f32x4 o[4];                                // o[nfo]: rows lg*4+r (q), cols nfo*16+lc (d)
#pragma unroll
  for (int nfo = 0; nfo < 4; ++nfo) o[nfo] = (f32x4){0.f, 0.f, 0.f, 0.f};
  float m = -1e30f, lsum = 0.f;              // lsum: per-lane PARTIAL over this lane's k-subset

  const int swz = ((l & 7) ^ (l >> 3)) * 16;  // pre-swizzled source slot (bytes)
  int kcoff[2], vcoff[4];
#pragma unroll
  for (int kk = 0; kk < 2; ++kk) kcoff[kk] = (kk * 64 + lg * 16) ^ ((lc & 7) << 4);
#pragma unroll
  for (int nfk = 0; nfk < 4; ++nfk) vcoff[nfk] = (nfk * 32 + lg * 8) ^ ((lc & 7) << 4);
  const int rowb = lc * 128;                  // byte offset of this lane's LDS row
  const int* mrow = maskp + b * TT;

  auto stage = [&](int buf, int c0) {
#pragma unroll
    for (int cc = 0; cc < 2; ++cc) {
      const int slot = w * 2 + cc;
      const int rr = slot * 8 + (l >> 3);
      gload16(Kp + (size_t)(b * TT + c0 + rr) * DD + h * DKK + (swz >> 1), &Kl[buf][slot * 512]);
      gload16(Vt + (size_t)((b * HH + h) * DKK + rr) * TT + c0 + (swz >> 1), &Vl[buf][slot * 512]);
    }
  };

  const int ntiles = (causal ? (q0 + 64) : TT) >> 6;
  stage(0, 0);
  __syncthreads();
  int cur = 0;
#pragma unroll 1
  for (int t = 0; t < ntiles; ++t) {
    if (t + 1 < ntiles) stage(cur ^ 1, (t + 1) * 64);
    const int c0 = t * 64;
    const char* kl = (const char*)Kl[cur];
    const char* vl = (const char*)Vl[cur];

    // S^T = mfma(K, Q): s[nf] covers k-cols nf*16 + lg*4 + r for q-row lc
    f32x4 s[4];
#pragma unroll
    for (int nf = 0; nf < 4; ++nf) s[nf] = (f32x4){0.f, 0.f, 0.f, 0.f};
#pragma unroll
    for (int nf = 0; nf < 4; ++nf)
#pragma unroll
      for (int kk = 0; kk < 2; ++kk) {
        bf16x8 kf = *(const bf16x8*)(kl + rowb + kcoff[kk] + nf * 2048);
        s[nf] = __builtin_amdgcn_mfma_f32_16x16x32_bf16(kf, qf[kk], s[nf], 0, 0, 0);
      }

    // padding mask: fast path skips all per-element work when tile fully alive
    const unsigned long long bal = __ballot(mrow[c0 + l] != 0);
    if (bal != ~0ull) {
#pragma unroll
      for (int nf = 0; nf < 4; ++nf) {
        const int4 mv = *(const int4*)&mrow[c0 + nf * 16 + lg * 4];
        const int mvr[4] = {mv.x, mv.y, mv.z, mv.w};
#pragma unroll
        for (int r = 0; r < 4; ++r)
          if (mvr[r] == 0) s[nf][r] = -1e30f;
      }
    }
    // causal: only the diagonal tile needs compares (earlier tiles: kg < q0 <= qr)
    if (causal && (t == ntiles - 1)) {
#pragma unroll
      for (int nf = 0; nf < 4; ++nf)
#pragma unroll
        for (int r = 0; r < 4; ++r) {
          const int kg = c0 + nf * 16 + lg * 4 + r;
          if (kg > qr) s[nf][r] = -1e30f;
        }
    }

    // tile max (clang fuses nested fmaxf to v_max3), reduce over lg (2 shuffles)
    float pm = fmaxf(fmaxf(fmaxf(s[0][0], s[0][1]), fmaxf(s[0][2], s[0][3])),
                     fmaxf(fmaxf(s[1][0], s[1][1]), fmaxf(s[1][2], s[1][3])));
    pm = fmaxf(pm, fmaxf(fmaxf(fmaxf(s[2][0], s[2][1]), fmaxf(s[2][2], s[2][3])),
                         fmaxf(fmaxf(s[3][0], s[3][1]), fmaxf(s[3][2], s[3][3]))));
    pm = fmaxf(pm, __shfl_xor(pm, 16, 64));
    pm = fmaxf(pm, __shfl_xor(pm, 32, 64));

    // T13 defer-rescale: only rescale when the running max grew by > 8
    // (or is still at the init value). All 4 lanes of a q-row agree on
    // (m, pm), so the uniform __all gate keeps per-lane partials consistent.
    if (!__all((m > -1e28f) && (pm <= m + 8.0f))) {
      const float mn = fmaxf(fmaxf(m, pm), -1e28f);
      const float al = fexp2(m - mn);
      m = mn;
      float alr[4];
#pragma unroll
      for (int r = 0; r < 4; ++r) alr[r] = __shfl(al, lg * 4 + r, 64);
#pragma unroll
      for (int nfo = 0; nfo < 4; ++nfo)
#pragma unroll
        for (int r = 0; r < 4; ++r) o[nfo][r] *= alr[r];
      lsum *= al;
    }

    // P = exp2(S - m): dead (-1e30) underflows to 0; values bounded by 2^8
    float ps = 0.f;
    bf16x4 pa[4];
#pragma unroll
    for (int nf = 0; nf < 4; ++nf) {
      const float p0 = fexp2(s[nf][0] - m);
      const float p1 = fexp2(s[nf][1] - m);
      const float p2 = fexp2(s[nf][2] - m);
      const float p3 = fexp2(s[nf][3] - m);
      ps += (p0 + p1) + (p2 + p3);
      union { unsigned int u[2]; bf16x4 v; } pk;
      pk.u[0] = cvtpk_bf16(p0, p1);
      pk.u[1] = cvtpk_bf16(p2, p3);
      pa[nf] = pk.v;
    }
    lsum += ps;   // per-lane partial; lg-reduce deferred to epilogue

    // O += P @ V via 16x16x16: A = pa[nfk] (in-register), B = Vl[d][t]
#pragma unroll
    for (int nfo = 0; nfo < 4; ++nfo)
#pragma unroll
      for (int nfk = 0; nfk < 4; ++nfk) {
        bf16x4 vb = *(const bf16x4*)(vl + rowb + vcoff[nfk] + nfo * 2048);
        o[nfo] = mfma16(pa[nfk], vb, o[nfo]);
      }

    __syncthreads();  // LDS reads of cur done; stage of cur^1 drained
    cur ^= 1;
  }

  // epilogue: complete the deferred lsum reduce (over lg), then normalize.
  lsum += __shfl_xor(lsum, 16, 64);
  lsum += __shfl_xor(lsum, 32, 64);
  float linv[4];
#pragma unroll
  for (int r = 0; r < 4; ++r) linv[r] = 1.0f / __shfl(lsum, lg * 4 + r, 64);
#pragma unroll
  for (int nfo = 0; nfo < 4; ++nfo) {
    const int dg = h * DKK + nfo * 16 + lc;
#pragma unroll
    for (int r = 0; r < 4; ++r) {
      const int qg = q0 + w * 16 + lg * 4 + r;
      Oc[(size_t)(b * TT + qg) * DD + dg] = f2bf(o[nfo][r] * linv[r]);
    }
  }
}

extern "C" void kernel_launch(void* const* d_in, const int* in_sizes, int n_in,
                              void* d_out, int out_size, void* d_ws, size_t ws_size,
                              hipStream_t stream)
{
  (void)in_sizes; (void)n_in; (void)out_size; (void)ws_size;
  const float* kf = (const float*)d_in[0];
  const float* qf = (const float*)d_in[1];
  const float* vf = (const float*)d_in[2];
  const int* mask = (const int*)d_in[3];
  const int* causal = (const int*)d_in[4];
  const float* Wf = (const float*)d_in[5];
  const float* bf = (const float*)d_in[6];

  const size_t MB = 1024 * 1024;
  char* ws = (char*)d_ws;
  unsigned short* kb = (unsigned short*)(ws);                 // 8 MiB
  unsigned short* qb = (unsigned short*)(ws + 8 * MB);        // 8 MiB
  unsigned short* vb = (unsigned short*)(ws + 16 * MB);       // 8 MiB
  unsigned short* Wb = (unsigned short*)(ws + 24 * MB);       // 2 MiB
  unsigned short* Kp = (unsigned short*)(ws + 26 * MB);       // 8 MiB
  unsigned short* Qp = (unsigned short*)(ws + 34 * MB);       // 8 MiB
  unsigned short* Vt = (unsigned short*)(ws + 42 * MB);       // 8 MiB
  unsigned short* Oc = kb;  // kb dead after projections

  f2b_all<<<dim3(2048), dim3(256), 0, stream>>>(kf, qf, vf, Wf, kb, qb, vb, Wb);
  gemm_proj<<<dim3(8, 96), dim3(256), 0, stream>>>(kb, qb, vb, Wb, bf, Kp, Qp, Vt);
  attn<<<dim3(32, 32), dim3(256), 0, stream>>>(Qp, Kp, Vt, mask, causal, Oc);
  gemm_out<<<dim3(8, 32), dim3(256), 0, stream>>>(Oc, Wb, bf, (float*)d_out);
}

// Round 14
// 127.468 us; speedup vs baseline: 1.2051x; 1.0539x over previous
//
#include <hip/hip_runtime.h>

#define TT 2048
#define DD 1024
#define HH 16
#define DKK 64
#define BB 2

typedef __attribute__((ext_vector_type(8))) short bf16x8;
typedef __attribute__((ext_vector_type(4))) short bf16x4;
typedef __attribute__((ext_vector_type(4))) float f32x4;
typedef __attribute__((ext_vector_type(4))) unsigned short us4;

__device__ __forceinline__ unsigned short f2bf(float f) {
  union { float f; unsigned int i; } v; v.f = f;
  unsigned int x = v.i;
  return (unsigned short)((x + 0x7fffu + ((x >> 16) & 1u)) >> 16);
}
__device__ __forceinline__ unsigned int cvtpk_bf16(float lo, float hi) {
  unsigned int r;
  asm("v_cvt_pk_bf16_f32 %0, %1, %2" : "=v"(r) : "v"(lo), "v"(hi));
  return r;
}
__device__ __forceinline__ void gload16(const void* g, void* l) {
  __builtin_amdgcn_global_load_lds((const __attribute__((address_space(1))) void*)g,
                                   (__attribute__((address_space(3))) void*)l,
                                   16, 0, 0);
}

#if defined(__has_builtin)
#if __has_builtin(__builtin_amdgcn_exp2f)
#define HAVE_EXP2 1
#endif
#if __has_builtin(__builtin_amdgcn_mfma_f32_16x16x16bf16_1k)
#define HAVE_MFMA16 1
#endif
#endif

__device__ __forceinline__ float fexp2(float x) {
#ifdef HAVE_EXP2
  return __builtin_amdgcn_exp2f(x);
#else
  return __builtin_exp2f(x);
#endif
}

__device__ __forceinline__ f32x4 mfma16(bf16x4 a, bf16x4 b, f32x4 c) {
#ifdef HAVE_MFMA16
  return __builtin_amdgcn_mfma_f32_16x16x16bf16_1k(a, b, c, 0, 0, 0);
#else
  asm volatile("v_mfma_f32_16x16x16_bf16 %0, %1, %2, %0\n\ts_nop 7\n\ts_nop 7"
               : "+v"(c) : "v"(a), "v"(b));
  return c;
#endif
}

// fp32 -> bf16 for k,q,v,W in one dispatch
__global__ __launch_bounds__(256)
void f2b_all(const float* __restrict__ k, const float* __restrict__ q,
             const float* __restrict__ v, const float* __restrict__ W,
             unsigned short* __restrict__ kb, unsigned short* __restrict__ qb,
             unsigned short* __restrict__ vb, unsigned short* __restrict__ Wb)
{
  const int n1 = (BB * TT * DD) / 4;   // 1048576 float4s per tensor
  const int nW = (DD * DD) / 4;        // 262144
  const int total = 3 * n1 + nW;
  int i = blockIdx.x * 256 + threadIdx.x;
  const int stride = gridDim.x * 256;
  for (; i < total; i += stride) {
    const float* src; unsigned short* dst; int j = i;
    if (j < n1)            { src = k; dst = kb; }
    else if (j < 2 * n1)   { src = q; dst = qb; j -= n1; }
    else if (j < 3 * n1)   { src = v; dst = vb; j -= 2 * n1; }
    else                   { src = W; dst = Wb; j -= 3 * n1; }
    const float4 f = ((const float4*)src)[j];
    us4 o;
    o[0] = f2bf(f.x); o[1] = f2bf(f.y); o[2] = f2bf(f.z); o[3] = f2bf(f.w);
    ((us4*)dst)[j] = o;
  }
}

// ---- GEMM machinery: 2-barrier double-buffered K-loop, BK=32 ----
// Tiles shrunk for TLP (both GEMMs are latency-bound, no pipe >30%):
// gemm_proj 128x64 (1536 blocks = 6/CU), gemm_out 64x64 (1024 = 4/CU).
// LDS rows 64B; XOR-swizzle (row&3)<<4 via pre-swizzled global source.
// Bijective XCD swizzle (n fast): A-strip-sharing blocks stay on one XCD.

// Fused K/Q/V projection: tile 128(m) x 64(n); grid (16, 96) = 1536 blocks.
__global__ __launch_bounds__(256)
void gemm_proj(const unsigned short* __restrict__ kb, const unsigned short* __restrict__ qb,
               const unsigned short* __restrict__ vb, const unsigned short* __restrict__ W,
               const float* __restrict__ bias,
               unsigned short* __restrict__ Kp, unsigned short* __restrict__ Qp,
               unsigned short* __restrict__ Vt)
{
  __shared__ unsigned short lA[2][128 * 32];
  __shared__ unsigned short lB[2][64 * 32];
  const int tid = threadIdx.x;
  const int w = tid >> 6, l = tid & 63;
  const int hw = blockIdx.y * gridDim.x + blockIdx.x;     // 0..1535
  const int virt = (hw & 7) * 192 + (hw >> 3);            // bijective XCD swizzle
  const int n0 = (virt & 15) * 64;                        // 16 n-blocks
  const int my = virt >> 4;                               // 0..95 m-strips
  const int grp = my >> 5;                                // 0:K 1:Q 2:V
  const int m0 = (my & 31) * 128;
  const unsigned short* A = grp == 0 ? kb : (grp == 1 ? qb : vb);
  const int wr = w >> 1, wc = w & 1;
  const int lg = l >> 4, lc = l & 15;

  f32x4 acc[4][2];
#pragma unroll
  for (int i = 0; i < 4; ++i)
#pragma unroll
    for (int j = 0; j < 2; ++j) acc[i][j] = (f32x4){0.f, 0.f, 0.f, 0.f};

  const int scolb = (((l & 3) ^ ((l >> 2) & 3)) * 16);  // pre-swizzled source slot

  auto stage = [&](int buf, int k0) {
#pragma unroll
    for (int cc = 0; cc < 2; ++cc) {              // A: 8 slots x 16 rows = 128
      const int slot = w * 2 + cc;
      const int row = slot * 16 + (l >> 2);
      gload16(A + (size_t)(m0 + row) * DD + k0 + (scolb >> 1), &lA[buf][slot * 512]);
    }
    {                                             // B: 4 slots x 16 rows = 64
      const int row = w * 16 + (l >> 2);
      gload16(W + (size_t)(n0 + row) * DD + k0 + (scolb >> 1), &lB[buf][w * 512]);
    }
  };

  stage(0, 0);
  __syncthreads();
  int cur = 0;
#pragma unroll 1
  for (int kt = 0; kt < 32; ++kt) {
    if (kt < 31) stage(cur ^ 1, (kt + 1) * 32);
    const char* la = (const char*)lA[cur];
    const char* lb = (const char*)lB[cur];
    bf16x8 af[4], bfr[2];
#pragma unroll
    for (int mf = 0; mf < 4; ++mf)
      af[mf] = *(const bf16x8*)(la + (wr * 64 + mf * 16 + lc) * 64 + ((lg * 16) ^ ((lc & 3) << 4)));
#pragma unroll
    for (int nf = 0; nf < 2; ++nf)
      bfr[nf] = *(const bf16x8*)(lb + (wc * 32 + nf * 16 + lc) * 64 + ((lg * 16) ^ ((lc & 3) << 4)));
#pragma unroll
    for (int mf = 0; mf < 4; ++mf)
#pragma unroll
      for (int nf = 0; nf < 2; ++nf)
        acc[mf][nf] = __builtin_amdgcn_mfma_f32_16x16x32_bf16(af[mf], bfr[nf], acc[mf][nf], 0, 0, 0);
    __syncthreads();
    cur ^= 1;
  }

  // Q gets 1/sqrt(DK) * log2(e) folded in (attn softmax runs in exp2 domain)
  const float scale = (grp == 1) ? 0.125f * 1.4426950408889634f : 1.0f;
#pragma unroll
  for (int nf = 0; nf < 2; ++nf) {
    const int colg = n0 + wc * 32 + nf * 16 + lc;
    const float bv = bias[colg];
#pragma unroll
    for (int mf = 0; mf < 4; ++mf) {
      const int rowg = m0 + wr * 64 + mf * 16 + lg * 4;
      if (grp < 2) {
        unsigned short* C = grp == 0 ? Kp : Qp;
#pragma unroll
        for (int r = 0; r < 4; ++r)
          C[(size_t)(rowg + r) * DD + colg] = f2bf(scale * (acc[mf][nf][r] + bv));
      } else {
        const int bb = rowg >> 11, t = rowg & (TT - 1);
        const int hh = colg >> 6, dk = colg & 63;
        us4 pk;
#pragma unroll
        for (int r = 0; r < 4; ++r) pk[r] = f2bf(acc[mf][nf][r] + bv);
        *(us4*)&Vt[((size_t)((bb * HH + hh) * DKK + dk)) * TT + t] = pk;
      }
    }
  }
}

// Final projection: C(fp32) = A @ W^T + bias; tile 64x64; grid (16,64)=1024.
__global__ __launch_bounds__(256)
void gemm_out(const unsigned short* __restrict__ A, const unsigned short* __restrict__ W,
              const float* __restrict__ bias, float* __restrict__ Cf)
{
  __shared__ unsigned short lA[2][64 * 32];
  __shared__ unsigned short lB[2][64 * 32];
  const int tid = threadIdx.x;
  const int w = tid >> 6, l = tid & 63;
  const int hw = blockIdx.y * gridDim.x + blockIdx.x;     // 0..1023
  const int virt = (hw & 7) * 128 + (hw >> 3);            // bijective XCD swizzle
  const int n0 = (virt & 15) * 64, m0 = (virt >> 4) * 64;
  const int wr = w >> 1, wc = w & 1;
  const int lg = l >> 4, lc = l & 15;

  f32x4 acc[2][2];
#pragma unroll
  for (int i = 0; i < 2; ++i)
#pragma unroll
    for (int j = 0; j < 2; ++j) acc[i][j] = (f32x4){0.f, 0.f, 0.f, 0.f};

  const int scolb = (((l & 3) ^ ((l >> 2) & 3)) * 16);

  auto stage = [&](int buf, int k0) {
    const int row = w * 16 + (l >> 2);                    // 4 slots x 16 rows
    gload16(A + (size_t)(m0 + row) * DD + k0 + (scolb >> 1), &lA[buf][w * 512]);
    gload16(W + (size_t)(n0 + row) * DD + k0 + (scolb >> 1), &lB[buf][w * 512]);
  };

  stage(0, 0);
  __syncthreads();
  int cur = 0;
#pragma unroll 1
  for (int kt = 0; kt < 32; ++kt) {
    if (kt < 31) stage(cur ^ 1, (kt + 1) * 32);
    const char* la = (const char*)lA[cur];
    const char* lb = (const char*)lB[cur];
    bf16x8 af[2], bfr[2];
#pragma unroll
    for (int mf = 0; mf < 2; ++mf)
      af[mf] = *(const bf16x8*)(la + (wr * 32 + mf * 16 + lc) * 64 + ((lg * 16) ^ ((lc & 3) << 4)));
#pragma unroll
    for (int nf = 0; nf < 2; ++nf)
      bfr[nf] = *(const bf16x8*)(lb + (wc * 32 + nf * 16 + lc) * 64 + ((lg * 16) ^ ((lc & 3) << 4)));
#pragma unroll
    for (int mf = 0; mf < 2; ++mf)
#pragma unroll
      for (int nf = 0; nf < 2; ++nf)
        acc[mf][nf] = __builtin_amdgcn_mfma_f32_16x16x32_bf16(af[mf], bfr[nf], acc[mf][nf], 0, 0, 0);
    __syncthreads();
    cur ^= 1;
  }

#pragma unroll
  for (int nf = 0; nf < 2; ++nf) {
    const int colg = n0 + wc * 32 + nf * 16 + lc;
    const float bv = bias[colg];
#pragma unroll
    for (int mf = 0; mf < 2; ++mf) {
      const int rowg = m0 + wr * 32 + mf * 16 + lg * 4;
#pragma unroll
      for (int r = 0; r < 4; ++r)
        Cf[(size_t)(rowg + r) * DD + colg] = acc[mf][nf][r] + bv;
    }
  }
}

// Flash attention (round-13 version, unchanged): swapped-operand QK^T,
// in-register P, exp2-domain softmax, T13 defer-rescale, deferred lsum
// reduce. QBLK=64, grid (32,32), heavy-first.
__global__ __launch_bounds__(256)
void attn(const unsigned short* __restrict__ Qp,
          const unsigned short* __restrict__ Kp,
          const unsigned short* __restrict__ Vt,
          const int* __restrict__ maskp,
          const int* __restrict__ causalp,
          unsigned short* __restrict__ Oc)
{
  __shared__ unsigned short Kl[2][64 * 64];
  __shared__ unsigned short Vl[2][64 * 64];
  const int tid = threadIdx.x;
  const int w = tid >> 6, l = tid & 63;
  const int bh = blockIdx.x;
  const int q0 = (31 - blockIdx.y) * 64;
  const int b = bh >> 4, h = bh & 15;
  const int lg = l >> 4, lc = l & 15;
  const int causal = causalp[0];
  const int qr = q0 + w * 16 + lc;          // this lane's q-row

  bf16x8 qf[2];
  {
    const unsigned short* qp = Qp + (size_t)(b * TT + qr) * DD + h * DKK + lg * 8;
    qf[0] = *(const bf16x8*)qp;
    qf[1] = *(const bf16x8*)(qp + 32);
  }
  f32x4 o[4];
#pragma unroll
  for (int nfo = 0; nfo < 4; ++nfo) o[nfo] = (f32x4){0.f, 0.f, 0.f, 0.f};
  float m = -1e30f, lsum = 0.f;              // lsum: per-lane partial

  const int swz = ((l & 7) ^ (l >> 3)) * 16;
  int kcoff[2], vcoff[4];
#pragma unroll
  for (int kk = 0; kk < 2; ++kk) kcoff[kk] = (kk * 64 + lg * 16) ^ ((lc & 7) << 4);
#pragma unroll
  for (int nfk = 0; nfk < 4; ++nfk) vcoff[nfk] = (nfk * 32 + lg * 8) ^ ((lc & 7) << 4);
  const int rowb = lc * 128;
  const int* mrow = maskp + b * TT;

  auto stage = [&](int buf, int c0) {
#pragma unroll
    for (int cc = 0; cc < 2; ++cc) {
      const int slot = w * 2 + cc;
      const int rr = slot * 8 + (l >> 3);
      gload16(Kp + (size_t)(b * TT + c0 + rr) * DD + h * DKK + (swz >> 1), &Kl[buf][slot * 512]);
      gload16(Vt + (size_t)((b * HH + h) * DKK + rr) * TT + c0 + (swz >> 1), &Vl[buf][slot * 512]);
    }
  };

  const int ntiles = (causal ? (q0 + 64) : TT) >> 6;
  stage(0, 0);
  __syncthreads();
  int cur = 0;
#pragma unroll 1
  for (int t = 0; t < ntiles; ++t) {
    if (t + 1 < ntiles) stage(cur ^ 1, (t + 1) * 64);
    const int c0 = t * 64;
    const char* kl = (const char*)Kl[cur];
    const char* vl = (const char*)Vl[cur];

    f32x4 s[4];
#pragma unroll
    for (int nf = 0; nf < 4; ++nf) s[nf] = (f32x4){0.f, 0.f, 0.f, 0.f};
#pragma unroll
    for (int nf = 0; nf < 4; ++nf)
#pragma unroll
      for (int kk = 0; kk < 2; ++kk) {
        bf16x8 kf = *(const bf16x8*)(kl + rowb + kcoff[kk] + nf * 2048);
        s[nf] = __builtin_amdgcn_mfma_f32_16x16x32_bf16(kf, qf[kk], s[nf], 0, 0, 0);
      }

    const unsigned long long bal = __ballot(mrow[c0 + l] != 0);
    if (bal != ~0ull) {
#pragma unroll
      for (int nf = 0; nf < 4; ++nf) {
        const int4 mv = *(const int4*)&mrow[c0 + nf * 16 + lg * 4];
        const int mvr[4] = {mv.x, mv.y, mv.z, mv.w};
#pragma unroll
        for (int r = 0; r < 4; ++r)
          if (mvr[r] == 0) s[nf][r] = -1e30f;
      }
    }
    if (causal && (t == ntiles - 1)) {
#pragma unroll
      for (int nf = 0; nf < 4; ++nf)
#pragma unroll
        for (int r = 0; r < 4; ++r) {
          const int kg = c0 + nf * 16 + lg * 4 + r;
          if (kg > qr) s[nf][r] = -1e30f;
        }
    }

    float pm = fmaxf(fmaxf(fmaxf(s[0][0], s[0][1]), fmaxf(s[0][2], s[0][3])),
                     fmaxf(fmaxf(s[1][0], s[1][1]), fmaxf(s[1][2], s[1][3])));
    pm = fmaxf(pm, fmaxf(fmaxf(fmaxf(s[2][0], s[2][1]), fmaxf(s[2][2], s[2][3])),
                         fmaxf(fmaxf(s[3][0], s[3][1]), fmaxf(s[3][2], s[3][3]))));
    pm = fmaxf(pm, __shfl_xor(pm, 16, 64));
    pm = fmaxf(pm, __shfl_xor(pm, 32, 64));

    // T13 defer-rescale
    if (!__all((m > -1e28f) && (pm <= m + 8.0f))) {
      const float mn = fmaxf(fmaxf(m, pm), -1e28f);
      const float al = fexp2(m - mn);
      m = mn;
      float alr[4];
#pragma unroll
      for (int r = 0; r < 4; ++r) alr[r] = __shfl(al, lg * 4 + r, 64);
#pragma unroll
      for (int nfo = 0; nfo < 4; ++nfo)
#pragma unroll
        for (int r = 0; r < 4; ++r) o[nfo][r] *= alr[r];
      lsum *= al;
    }

    float ps = 0.f;
    bf16x4 pa[4];
#pragma unroll
    for (int nf = 0; nf < 4; ++nf) {
      const float p0 = fexp2(s[nf][0] - m);
      const float p1 = fexp2(s[nf][1] - m);
      const float p2 = fexp2(s[nf][2] - m);
      const float p3 = fexp2(s[nf][3] - m);
      ps += (p0 + p1) + (p2 + p3);
      union { unsigned int u[2]; bf16x4 v; } pk;
      pk.u[0] = cvtpk_bf16(p0, p1);
      pk.u[1] = cvtpk_bf16(p2, p3);
      pa[nf] = pk.v;
    }
    lsum += ps;   // per-lane partial; lg-reduce deferred to epilogue

#pragma unroll
    for (int nfo = 0; nfo < 4; ++nfo)
#pragma unroll
      for (int nfk = 0; nfk < 4; ++nfk) {
        bf16x4 vb = *(const bf16x4*)(vl + rowb + vcoff[nfk] + nfo * 2048);
        o[nfo] = mfma16(pa[nfk], vb, o[nfo]);
      }

    __syncthreads();
    cur ^= 1;
  }

  lsum += __shfl_xor(lsum, 16, 64);
  lsum += __shfl_xor(lsum, 32, 64);
  float linv[4];
#pragma unroll
  for (int r = 0; r < 4; ++r) linv[r] = 1.0f / __shfl(lsum, lg * 4 + r, 64);
#pragma unroll
  for (int nfo = 0; nfo < 4; ++nfo) {
    const int dg = h * DKK + nfo * 16 + lc;
#pragma unroll
    for (int r = 0; r < 4; ++r) {
      const int qg = q0 + w * 16 + lg * 4 + r;
      Oc[(size_t)(b * TT + qg) * DD + dg] = f2bf(o[nfo][r] * linv[r]);
    }
  }
}

extern "C" void kernel_launch(void* const* d_in, const int* in_sizes, int n_in,
                              void* d_out, int out_size, void* d_ws, size_t ws_size,
                              hipStream_t stream)
{
  (void)in_sizes; (void)n_in; (void)out_size; (void)ws_size;
  const float* kf = (const float*)d_in[0];
  const float* qf = (const float*)d_in[1];
  const float* vf = (const float*)d_in[2];
  const int* mask = (const int*)d_in[3];
  const int* causal = (const int*)d_in[4];
  const float* Wf = (const float*)d_in[5];
  const float* bf = (const float*)d_in[6];

  const size_t MB = 1024 * 1024;
  char* ws = (char*)d_ws;
  unsigned short* kb = (unsigned short*)(ws);                 // 8 MiB
  unsigned short* qb = (unsigned short*)(ws + 8 * MB);        // 8 MiB
  unsigned short* vb = (unsigned short*)(ws + 16 * MB);       // 8 MiB
  unsigned short* Wb = (unsigned short*)(ws + 24 * MB);       // 2 MiB
  unsigned short* Kp = (unsigned short*)(ws + 26 * MB);       // 8 MiB
  unsigned short* Qp = (unsigned short*)(ws + 34 * MB);       // 8 MiB
  unsigned short* Vt = (unsigned short*)(ws + 42 * MB);       // 8 MiB
  unsigned short* Oc = kb;  // kb dead after projections

  f2b_all<<<dim3(2048), dim3(256), 0, stream>>>(kf, qf, vf, Wf, kb, qb, vb, Wb);
  gemm_proj<<<dim3(16, 96), dim3(256), 0, stream>>>(kb, qb, vb, Wb, bf, Kp, Qp, Vt);
  attn<<<dim3(32, 32), dim3(256), 0, stream>>>(Qp, Kp, Vt, mask, causal, Oc);
  gemm_out<<<dim3(16, 64), dim3(256), 0, stream>>>(Oc, Wb, bf, (float*)d_out);
}